// Round 1
// baseline (131.694 us; speedup 1.0000x reference)
//
#include <hip/hip_runtime.h>
#include <stdint.h>

#define BATCH 8192
#define DIM 256
#define NSPLIT 8
#define BM 128
#define BN 64
#define COLS_PER_SPLIT (BATCH / NSPLIT)   // 1024
#define NTILES (COLS_PER_SPLIT / BN)      // 16

typedef unsigned short ushort_t;
typedef __bf16 bf16x8 __attribute__((ext_vector_type(8)));
typedef float floatx4 __attribute__((ext_vector_type(4)));

__device__ __forceinline__ ushort_t f2bf(float f) {
    uint32_t u = __float_as_uint(f);
    u += 0x7fffu + ((u >> 16) & 1u);   // RNE; inputs are finite gaussians
    return (ushort_t)(u >> 16);
}

// ---------------------------------------------------------------------------
// Prep: bf16-convert pred/target into MFMA-fragment-ready layouts.
// A' layout (elements): [rowtile=i>>4][kc=k>>5][lane=((k>>3)&3)*16 + (i&15)][k&7]
// B' layout (elements): [tile=j>>6][kc=k>>5][ntile=(j>>4)&3][lane=((k>>3)&3)*16 + (j&15)][k&7]
// so a wave's ds_read_b128 per fragment is lane-sequential (2-way bank alias = free)
// and a 32KB col-tile of B' is globally contiguous (global_load_lds width=16 works).
// Also: t2[j] = ||target_j||^2, diag[i] = pred_i . target_i (both fp32).
// ---------------------------------------------------------------------------
__global__ __launch_bounds__(256) void prep_kernel(
        const float* __restrict__ pred, const float* __restrict__ target,
        ushort_t* __restrict__ Ap, ushort_t* __restrict__ Bp,
        float* __restrict__ t2, float* __restrict__ diag) {
    const int lane = threadIdx.x & 63;
    const int wave = threadIdx.x >> 6;
    const int row  = blockIdx.x * 4 + wave;

    const float4 p4 = *(const float4*)(pred + (size_t)row * DIM + lane * 4);
    const float4 t4 = *(const float4*)(target + (size_t)row * DIM + lane * 4);

    // this lane covers k = lane*4 .. lane*4+3
    const int kc = lane >> 3;            // k >> 5
    const int kg = (lane >> 1) & 3;      // (k >> 3) & 3
    const int e0 = (lane & 1) * 4;       // k & 7 (base of the 4)

    {   // A' (pred)
        const int rowtile = row >> 4, m15 = row & 15;
        const size_t off = (size_t)rowtile * 4096 + kc * 512 + (kg * 16 + m15) * 8 + e0;
        ushort4 v;
        v.x = f2bf(p4.x); v.y = f2bf(p4.y); v.z = f2bf(p4.z); v.w = f2bf(p4.w);
        *(ushort4*)(Ap + off) = v;
    }
    {   // B' (target)
        const int tile = row >> 6, ntile = (row >> 4) & 3, n15 = row & 15;
        const size_t off = (size_t)tile * 16384 + kc * 2048 + ntile * 512 + (kg * 16 + n15) * 8 + e0;
        ushort4 v;
        v.x = f2bf(t4.x); v.y = f2bf(t4.y); v.z = f2bf(t4.z); v.w = f2bf(t4.w);
        *(ushort4*)(Bp + off) = v;
    }

    float dsum = p4.x * t4.x + p4.y * t4.y + p4.z * t4.z + p4.w * t4.w;
    float tsum = t4.x * t4.x + t4.y * t4.y + t4.z * t4.z + t4.w * t4.w;
#pragma unroll
    for (int off = 32; off > 0; off >>= 1) {
        dsum += __shfl_xor(dsum, off);
        tsum += __shfl_xor(tsum, off);
    }
    if (lane == 0) {
        diag[row] = dsum;
        t2[row]   = tsum;
    }
}

// ---------------------------------------------------------------------------
// Main: per WG: 128 rows x 1024 cols.  4 waves, each 32 rows (2 m-subtiles).
// A fragments register-resident (64 VGPR/lane).  B col-tile (64x256 bf16,
// 32 KB) staged to LDS via global_load_lds width=16.  Online logsumexp kept
// per-lane (each lane tracks its own column slots); one 16-lane combine at end.
// ---------------------------------------------------------------------------
__global__ __launch_bounds__(256, 2) void main_kernel(
        const ushort_t* __restrict__ Ap, const ushort_t* __restrict__ Bp,
        const float* __restrict__ t2, const float* __restrict__ sigma,
        float2* __restrict__ partials) {
    __shared__ __align__(16) ushort_t ldsB[BN * DIM];   // 32 KB

    const int lane   = threadIdx.x & 63;
    const int wave   = threadIdx.x >> 6;
    const int rowBlk = blockIdx.x;    // 0..63
    const int split  = blockIdx.y;    // 0..7

    const float sg = sigma[0];
    const float inv_nv = 1.0f / (sg * sg);

    // resident A fragments: rows rowBlk*128 + wave*32 + mt*16 + (lane&15)
    bf16x8 afrag[2][8];
#pragma unroll
    for (int mt = 0; mt < 2; ++mt) {
        const int rowtile = rowBlk * 8 + wave * 2 + mt;
        const ushort_t* base = Ap + (size_t)rowtile * 4096 + lane * 8;
#pragma unroll
        for (int kc = 0; kc < 8; ++kc)
            afrag[mt][kc] = *(const bf16x8*)(base + kc * 512);
    }

    const float NEG_INF = -__builtin_inff();
    float mrun[2][4], lrun[2][4];
#pragma unroll
    for (int mt = 0; mt < 2; ++mt)
#pragma unroll
        for (int r = 0; r < 4; ++r) { mrun[mt][r] = NEG_INF; lrun[mt][r] = 0.0f; }

    for (int ct = 0; ct < NTILES; ++ct) {
        const int j0 = split * COLS_PER_SPLIT + ct * BN;

        // stage contiguous 32 KB B' tile: 32 wave-instrs x (64 lanes x 16 B)
        {
            const char* gbase = (const char*)(Bp + (size_t)(j0 >> 6) * 16384);
#pragma unroll
            for (int q = 0; q < 8; ++q) {
                const int chunk = wave * 8 + q;                 // 0..31
                const void* g = gbase + chunk * 1024 + (size_t)lane * 16;
                void* l = (char*)ldsB + chunk * 1024;           // wave-uniform base
                __builtin_amdgcn_global_load_lds(
                    (const __attribute__((address_space(1))) void*)g,
                    (__attribute__((address_space(3))) void*)l,
                    16, 0, 0);
            }
        }
        __syncthreads();

        floatx4 acc[2][4];
#pragma unroll
        for (int mt = 0; mt < 2; ++mt)
#pragma unroll
            for (int nt = 0; nt < 4; ++nt)
                acc[mt][nt] = (floatx4){0.f, 0.f, 0.f, 0.f};

#pragma unroll
        for (int kc = 0; kc < 8; ++kc) {
#pragma unroll
            for (int nt = 0; nt < 4; ++nt) {
                const bf16x8 bfrag = *(const bf16x8*)(ldsB + kc * 2048 + nt * 512 + lane * 8);
                acc[0][nt] = __builtin_amdgcn_mfma_f32_16x16x32_bf16(afrag[0][kc], bfrag, acc[0][nt], 0, 0, 0);
                acc[1][nt] = __builtin_amdgcn_mfma_f32_16x16x32_bf16(afrag[1][kc], bfrag, acc[1][nt], 0, 0, 0);
            }
        }

        float tv[4];
#pragma unroll
        for (int nt = 0; nt < 4; ++nt)
            tv[nt] = t2[j0 + nt * 16 + (lane & 15)];

        __syncthreads();   // all LDS reads issued+consumed before next stage

        // online logsumexp update; lane tracks only its own column slots
#pragma unroll
        for (int mt = 0; mt < 2; ++mt) {
#pragma unroll
            for (int r = 0; r < 4; ++r) {
                const float v0 = (acc[mt][0][r] - 0.5f * tv[0]) * inv_nv;
                const float v1 = (acc[mt][1][r] - 0.5f * tv[1]) * inv_nv;
                const float v2 = (acc[mt][2][r] - 0.5f * tv[2]) * inv_nv;
                const float v3 = (acc[mt][3][r] - 0.5f * tv[3]) * inv_nv;
                const float vmax = fmaxf(fmaxf(v0, v1), fmaxf(v2, v3));
                const float mold = mrun[mt][r];
                const float mnew = fmaxf(mold, vmax);
                float l = lrun[mt][r] * __expf(mold - mnew);
                l += __expf(v0 - mnew);
                l += __expf(v1 - mnew);
                l += __expf(v2 - mnew);
                l += __expf(v3 - mnew);
                mrun[mt][r] = mnew;
                lrun[mt][r] = l;
            }
        }
    }

    // combine the 16 column-slot lanes (xor over low 4 lane bits stays in-row)
#pragma unroll
    for (int mt = 0; mt < 2; ++mt) {
#pragma unroll
        for (int r = 0; r < 4; ++r) {
            float m = mrun[mt][r], l = lrun[mt][r];
#pragma unroll
            for (int mask = 1; mask < 16; mask <<= 1) {
                const float mo = __shfl_xor(m, mask);
                const float lo = __shfl_xor(l, mask);
                const float mn = fmaxf(m, mo);
                l = l * __expf(m - mn) + lo * __expf(mo - mn);
                m = mn;
            }
            if ((lane & 15) == 0) {
                const int rw = rowBlk * BM + wave * 32 + mt * 16 + (lane >> 4) * 4 + r;
                partials[(size_t)split * BATCH + rw] = make_float2(m, l);
            }
        }
    }
}

// ---------------------------------------------------------------------------
// Finish: combine split partials per row, mean over rows, scale by -2*sigma^2.
// ---------------------------------------------------------------------------
__global__ __launch_bounds__(256) void finish_kernel(
        const float2* __restrict__ partials, const float* __restrict__ t2,
        const float* __restrict__ diag, const float* __restrict__ sigma,
        float* __restrict__ out) {
    __shared__ float red[256];
    const int tid = threadIdx.x;
    const float sg = sigma[0];
    const float nv = sg * sg;
    const float inv_nv = 1.0f / nv;

    float acc = 0.0f;
    for (int row = tid; row < BATCH; row += 256) {
        float m = -__builtin_inff();
        float2 p[NSPLIT];
#pragma unroll
        for (int s = 0; s < NSPLIT; ++s) {
            p[s] = partials[(size_t)s * BATCH + row];
            m = fmaxf(m, p[s].x);
        }
        float L = 0.0f;
#pragma unroll
        for (int s = 0; s < NSPLIT; ++s)
            L += p[s].y * __expf(p[s].x - m);
        const float lse = m + __logf(L);
        const float d = (diag[row] - 0.5f * t2[row]) * inv_nv;
        acc += d - lse;
    }
    red[tid] = acc;
    __syncthreads();
    for (int s = 128; s > 0; s >>= 1) {
        if (tid < s) red[tid] += red[tid + s];
        __syncthreads();
    }
    if (tid == 0) out[0] = -2.0f * nv * red[0] / (float)BATCH;
}

extern "C" void kernel_launch(void* const* d_in, const int* in_sizes, int n_in,
                              void* d_out, int out_size, void* d_ws, size_t ws_size,
                              hipStream_t stream) {
    const float* pred   = (const float*)d_in[0];
    const float* target = (const float*)d_in[1];
    const float* sigma  = (const float*)d_in[2];
    float* out = (float*)d_out;

    char* ws = (char*)d_ws;
    ushort_t* Ap  = (ushort_t*)(ws);                                  // 4 MB
    ushort_t* Bp  = (ushort_t*)(ws + (size_t)BATCH * DIM * 2);        // 4 MB
    float* t2     = (float*)(ws + (size_t)BATCH * DIM * 4);           // 32 KB
    float* diag   = (float*)(ws + (size_t)BATCH * DIM * 4 + BATCH * 4);
    float2* parts = (float2*)(ws + (size_t)BATCH * DIM * 4 + (size_t)BATCH * 8);

    prep_kernel<<<BATCH / 4, 256, 0, stream>>>(pred, target, Ap, Bp, t2, diag);
    main_kernel<<<dim3(BATCH / BM, NSPLIT), 256, 0, stream>>>(Ap, Bp, t2, sigma, parts);
    finish_kernel<<<1, 256, 0, stream>>>(parts, t2, diag, sigma, out);
}

// Round 2
// 119.939 us; speedup vs baseline: 1.0980x; 1.0980x over previous
//
#include <hip/hip_runtime.h>
#include <stdint.h>

#define BATCH 8192
#define DIM 256
#define NSPLIT 8
#define BM 128
#define BN 64
#define COLS_PER_SPLIT (BATCH / NSPLIT)   // 1024
#define NTILES (COLS_PER_SPLIT / BN)      // 16
#define LOG2E 1.4426950408889634f
#define LN2   0.6931471805599453f

typedef unsigned short ushort_t;
typedef __bf16 bf16x8 __attribute__((ext_vector_type(8)));
typedef float floatx4 __attribute__((ext_vector_type(4)));
typedef float floatx2 __attribute__((ext_vector_type(2)));

__device__ __forceinline__ float fast_exp2(float x) {
#if __has_builtin(__builtin_amdgcn_exp2f)
    return __builtin_amdgcn_exp2f(x);
#else
    return exp2f(x);
#endif
}

__device__ __forceinline__ ushort_t f2bf(float f) {
    uint32_t u = __float_as_uint(f);
    u += 0x7fffu + ((u >> 16) & 1u);   // RNE; inputs are finite gaussians
    return (ushort_t)(u >> 16);
}

// ---------------------------------------------------------------------------
// Prep v2: block = one 16-row tile. Coalesced fp32 loads -> bf16 -> LDS in
// final fragment layout -> fully-coalesced 16B stores (old version did 8B
// scattered stores at ~12% efficiency). Also t2[j], diag[i] in fp32.
// A'[rowtile][kc][kg*16+r][e] ; B'[rt>>2][kc][rt&3][kg*16+r][e]
// ---------------------------------------------------------------------------
__global__ __launch_bounds__(256) void prep_kernel(
        const float* __restrict__ pred, const float* __restrict__ target,
        ushort_t* __restrict__ Ap, ushort_t* __restrict__ Bp,
        float* __restrict__ t2, float* __restrict__ diag) {
    __shared__ __align__(16) ushort_t ldsA[4096];
    __shared__ __align__(16) ushort_t ldsB[4096];
    const int t = threadIdx.x;
    const int r = t >> 4, c = t & 15;
    const int rt = blockIdx.x;
    const int row = rt * 16 + r;

    float dsum = 0.f, tsum = 0.f;
#pragma unroll
    for (int q = 0; q < 4; ++q) {
        const int k0 = q * 64 + c * 4;
        const float4 p4 = *(const float4*)(pred + (size_t)row * DIM + k0);
        const float4 t4 = *(const float4*)(target + (size_t)row * DIM + k0);
        dsum += p4.x * t4.x + p4.y * t4.y + p4.z * t4.z + p4.w * t4.w;
        tsum += t4.x * t4.x + t4.y * t4.y + t4.z * t4.z + t4.w * t4.w;
        const int kc = 2 * q + (c >> 3);
        const int kg = (c >> 1) & 3;
        const int e  = (c & 1) * 4;
        const int off = kc * 512 + kg * 128 + r * 8 + e;
        ushort4 pv, tv;
        pv.x = f2bf(p4.x); pv.y = f2bf(p4.y); pv.z = f2bf(p4.z); pv.w = f2bf(p4.w);
        tv.x = f2bf(t4.x); tv.y = f2bf(t4.y); tv.z = f2bf(t4.z); tv.w = f2bf(t4.w);
        *(ushort4*)(ldsA + off) = pv;
        *(ushort4*)(ldsB + off) = tv;
    }
#pragma unroll
    for (int mask = 1; mask < 16; mask <<= 1) {
        dsum += __shfl_xor(dsum, mask);
        tsum += __shfl_xor(tsum, mask);
    }
    if (c == 0) { diag[row] = dsum; t2[row] = tsum; }
    __syncthreads();

    const size_t abase = (size_t)rt * 4096;
    const size_t bbase = (size_t)(rt >> 2) * 16384 + (size_t)(rt & 3) * 512;
#pragma unroll
    for (int i = 0; i < 2; ++i) {
        const int g = i * 256 + t;
        const uint4 va = *(const uint4*)(ldsA + g * 8);
        const uint4 vb = *(const uint4*)(ldsB + g * 8);
        *(uint4*)(Ap + abase + (size_t)g * 8) = va;
        *(uint4*)(Bp + bbase + (size_t)(g >> 6) * 2048 + (size_t)(g & 63) * 8) = vb;
    }
}

// ---------------------------------------------------------------------------
// Main: 128 rows x 1024 cols per WG. A fragments register-resident. B tile
// (32 KB) via global_load_lds width=16, issued BEFORE the epilogue so the
// barrier's vmcnt(0) drain is covered by ~900 cyc of epilogue VALU.
// Logsumexp: log2 domain, per-slot FIXED offset m set from tile 0's max
// (clamped >= -108*c1 so 2^(v-m) can never overflow fp32); no per-tile
// rescale, no running max. Packed float2 epilogue math.
// ---------------------------------------------------------------------------
__global__ __launch_bounds__(256, 2) void main_kernel(
        const ushort_t* __restrict__ Ap, const ushort_t* __restrict__ Bp,
        const float* __restrict__ t2, const float* __restrict__ sigma,
        float2* __restrict__ partials) {
    __shared__ __align__(16) ushort_t ldsB[BN * DIM];   // 32 KB

    const int lane   = threadIdx.x & 63;
    const int wave   = threadIdx.x >> 6;
    const int rowBlk = blockIdx.x;    // 0..63
    const int split  = blockIdx.y;    // 0..7

    const float sg = sigma[0];
    const float inv_nv = 1.0f / (sg * sg);
    const float c1 = LOG2E * inv_nv;        // logits(log2) = dot*c1 + t2*c2
    const float c2 = -0.5f * c1;
    const float floor2 = -108.0f * c1;      // overflow-safe offset floor

    // resident A fragments
    bf16x8 afrag[2][8];
#pragma unroll
    for (int mt = 0; mt < 2; ++mt) {
        const ushort_t* base = Ap + (size_t)(rowBlk * 8 + wave * 2 + mt) * 4096 + lane * 8;
#pragma unroll
        for (int kc = 0; kc < 8; ++kc)
            afrag[mt][kc] = *(const bf16x8*)(base + kc * 512);
    }

    floatx2 m2[2][2], l2[2][2];
#pragma unroll
    for (int mt = 0; mt < 2; ++mt)
#pragma unroll
        for (int rp = 0; rp < 2; ++rp) {
            m2[mt][rp] = (floatx2){floor2, floor2};
            l2[mt][rp] = (floatx2){0.f, 0.f};
        }

    // stage tile 0
    {
        const char* gbase = (const char*)(Bp + (size_t)(split * 16) * 16384);
#pragma unroll
        for (int q = 0; q < 8; ++q) {
            const int chunk = wave * 8 + q;
            __builtin_amdgcn_global_load_lds(
                (const __attribute__((address_space(1))) void*)(gbase + chunk * 1024 + (size_t)lane * 16),
                (__attribute__((address_space(3))) void*)((char*)ldsB + chunk * 1024),
                16, 0, 0);
        }
    }
    __syncthreads();

    for (int ct = 0; ct < NTILES; ++ct) {
        const int j0 = split * COLS_PER_SPLIT + ct * BN;

        // issue t2 loads early; consumed in epilogue (latency hidden by MFMA)
        float t2v[4];
#pragma unroll
        for (int nt = 0; nt < 4; ++nt)
            t2v[nt] = t2[j0 + nt * 16 + (lane & 15)];

        floatx4 acc[2][4];
#pragma unroll
        for (int mt = 0; mt < 2; ++mt)
#pragma unroll
            for (int nt = 0; nt < 4; ++nt)
                acc[mt][nt] = (floatx4){0.f, 0.f, 0.f, 0.f};

#pragma unroll
        for (int kc = 0; kc < 8; ++kc) {
#pragma unroll
            for (int nt = 0; nt < 4; ++nt) {
                const bf16x8 bfrag = *(const bf16x8*)(ldsB + kc * 2048 + nt * 512 + lane * 8);
                acc[0][nt] = __builtin_amdgcn_mfma_f32_16x16x32_bf16(afrag[0][kc], bfrag, acc[0][nt], 0, 0, 0);
                acc[1][nt] = __builtin_amdgcn_mfma_f32_16x16x32_bf16(afrag[1][kc], bfrag, acc[1][nt], 0, 0, 0);
            }
        }

        __syncthreads();   // all waves' LDS reads complete

        // stage NEXT tile now; epilogue below covers its latency
        if (ct + 1 < NTILES) {
            const char* gbase = (const char*)(Bp + (size_t)(split * 16 + ct + 1) * 16384);
#pragma unroll
            for (int q = 0; q < 8; ++q) {
                const int chunk = wave * 8 + q;
                __builtin_amdgcn_global_load_lds(
                    (const __attribute__((address_space(1))) void*)(gbase + chunk * 1024 + (size_t)lane * 16),
                    (__attribute__((address_space(3))) void*)((char*)ldsB + chunk * 1024),
                    16, 0, 0);
            }
        }

        float tvc[4];
#pragma unroll
        for (int nt = 0; nt < 4; ++nt) tvc[nt] = t2v[nt] * c2;

        if (ct == 0) {
#pragma unroll
            for (int mt = 0; mt < 2; ++mt)
#pragma unroll
                for (int rp = 0; rp < 2; ++rp) {
                    floatx2 v[4];
#pragma unroll
                    for (int nt = 0; nt < 4; ++nt) {
                        const floatx2 a = (floatx2){acc[mt][nt][2 * rp], acc[mt][nt][2 * rp + 1]};
                        v[nt] = a * c1 + tvc[nt];
                    }
                    floatx2 mm = __builtin_elementwise_max(
                        __builtin_elementwise_max(v[0], v[1]),
                        __builtin_elementwise_max(v[2], v[3]));
                    mm = __builtin_elementwise_max(mm, (floatx2){floor2, floor2});
                    m2[mt][rp] = mm;
                    floatx2 s = (floatx2){0.f, 0.f};
#pragma unroll
                    for (int nt = 0; nt < 4; ++nt) {
                        s.x += fast_exp2(v[nt].x - mm.x);
                        s.y += fast_exp2(v[nt].y - mm.y);
                    }
                    l2[mt][rp] = s;
                }
        } else {
#pragma unroll
            for (int mt = 0; mt < 2; ++mt)
#pragma unroll
                for (int rp = 0; rp < 2; ++rp) {
                    const floatx2 mm = m2[mt][rp];
                    floatx2 s = l2[mt][rp];
#pragma unroll
                    for (int nt = 0; nt < 4; ++nt) {
                        const floatx2 a = (floatx2){acc[mt][nt][2 * rp], acc[mt][nt][2 * rp + 1]};
                        const floatx2 v = a * c1 + tvc[nt] - mm;
                        s.x += fast_exp2(v.x);
                        s.y += fast_exp2(v.y);
                    }
                    l2[mt][rp] = s;
                }
        }

        __syncthreads();   // staging for ct+1 drained (covered by epilogue)
    }

    // combine the 16 column-slot lanes per row
#pragma unroll
    for (int mt = 0; mt < 2; ++mt)
#pragma unroll
        for (int rp = 0; rp < 2; ++rp)
#pragma unroll
            for (int z = 0; z < 2; ++z) {
                float m = m2[mt][rp][z];
                float l = l2[mt][rp][z];
#pragma unroll
                for (int mask = 1; mask < 16; mask <<= 1) {
                    const float mo = __shfl_xor(m, mask);
                    const float lo = __shfl_xor(l, mask);
                    const float mn = fmaxf(m, mo);
                    l = l * fast_exp2(m - mn) + lo * fast_exp2(mo - mn);
                    m = mn;
                }
                if ((lane & 15) == 0) {
                    const int r  = rp * 2 + z;
                    const int rw = rowBlk * BM + wave * 32 + mt * 16 + (lane >> 4) * 4 + r;
                    partials[(size_t)split * BATCH + rw] = make_float2(m, l);
                }
            }
}

// ---------------------------------------------------------------------------
// Finish: combine split partials (log2 domain), mean, scale by 2*sigma^2.
// ---------------------------------------------------------------------------
__global__ __launch_bounds__(256) void finish_kernel(
        const float2* __restrict__ partials, const float* __restrict__ t2,
        const float* __restrict__ diag, const float* __restrict__ sigma,
        float* __restrict__ out) {
    __shared__ float red[256];
    const int tid = threadIdx.x;
    const float sg = sigma[0];
    const float nv = sg * sg;
    const float inv_nv = 1.0f / nv;

    float acc = 0.0f;
    for (int row = tid; row < BATCH; row += 256) {
        float m = -__builtin_inff();
        float2 p[NSPLIT];
#pragma unroll
        for (int s = 0; s < NSPLIT; ++s) {
            p[s] = partials[(size_t)s * BATCH + row];
            m = fmaxf(m, p[s].x);
        }
        float L = 0.0f;
#pragma unroll
        for (int s = 0; s < NSPLIT; ++s)
            L += p[s].y * fast_exp2(p[s].x - m);
        const float lse_nat = LN2 * (m + __log2f(L));
        const float d = (diag[row] - 0.5f * t2[row]) * inv_nv;
        acc += lse_nat - d;
    }
    red[tid] = acc;
    __syncthreads();
    for (int s = 128; s > 0; s >>= 1) {
        if (tid < s) red[tid] += red[tid + s];
        __syncthreads();
    }
    if (tid == 0) out[0] = 2.0f * nv * red[0] / (float)BATCH;
}

extern "C" void kernel_launch(void* const* d_in, const int* in_sizes, int n_in,
                              void* d_out, int out_size, void* d_ws, size_t ws_size,
                              hipStream_t stream) {
    const float* pred   = (const float*)d_in[0];
    const float* target = (const float*)d_in[1];
    const float* sigma  = (const float*)d_in[2];
    float* out = (float*)d_out;

    char* ws = (char*)d_ws;
    ushort_t* Ap  = (ushort_t*)(ws);                                  // 4 MB
    ushort_t* Bp  = (ushort_t*)(ws + (size_t)BATCH * DIM * 2);        // 4 MB
    float* t2     = (float*)(ws + (size_t)BATCH * DIM * 4);           // 32 KB
    float* diag   = (float*)(ws + (size_t)BATCH * DIM * 4 + BATCH * 4);
    float2* parts = (float2*)(ws + (size_t)BATCH * DIM * 4 + (size_t)BATCH * 8);

    prep_kernel<<<BATCH / 16, 256, 0, stream>>>(pred, target, Ap, Bp, t2, diag);
    main_kernel<<<dim3(BATCH / BM, NSPLIT), 256, 0, stream>>>(Ap, Bp, t2, sigma, parts);
    finish_kernel<<<1, 256, 0, stream>>>(parts, t2, diag, sigma, out);
}